// Round 11
// baseline (995.199 us; speedup 1.0000x reference)
//
#include <hip/hip_runtime.h>
#include <hip/hip_bf16.h>

typedef __hip_bfloat16 bf16;
typedef unsigned short u16;
typedef unsigned int u32;

#define DD 128           // feature dim
#define NG 200           // graphs
#define NL 5             // GCN layers
#define BETA_F 0.007782140442054161f   // log(1/128 + 1)
#define BN_EPS_F 1e-5f
#define WSTRIDE 136      // padded W' row stride (bf16 elems); 128x136 per layer
#define WELEMS (DD * WSTRIDE)
#define CVT_BLOCKS 1024

typedef __attribute__((ext_vector_type(8))) short bf16x8v;
typedef __attribute__((ext_vector_type(4))) float f32x4v;

// ---- dtype-generic load helpers (flag-selected, wave-uniform) ----

template<typename T> struct LD;
template<> struct LD<float> {
    static __device__ __forceinline__ float f(const void* p, size_t i) {
        return ((const float*)p)[i];
    }
};
template<> struct LD<bf16> {
    static __device__ __forceinline__ float f(const void* p, size_t i) {
        return __bfloat162float(((const bf16*)p)[i]);
    }
};
template<typename T> struct ST;
template<> struct ST<float> {
    static __device__ __forceinline__ void s(void* p, size_t i, float v) {
        ((float*)p)[i] = v;
    }
};
template<> struct ST<bf16> {
    static __device__ __forceinline__ void s(void* p, size_t i, float v) {
        ((bf16*)p)[i] = __float2bfloat16(v);
    }
};

// ---------------- k_init: interleaved cvt+count, then prepw, bounds ------------
// blocks [0, 2*CVT): alternate count(b&1==0)/cvt(b&1==1) so atomic-bound and
// BW-bound roles co-reside per CU (overlap, not serialize).
// blocks [2*CVT, CVT+CB): remaining count blocks.
// next NL: prepw (W' = beta*W + (1-beta)*I, padded n-major, + fp32 bias)
// last 1: bounds (graph start offsets; gid sorted) + flag write
template<typename TF>
__device__ __forceinline__ void prepw_body(int l, const void* gcn_w, const void* gcn_b,
        bf16* __restrict__ wtp, float* __restrict__ biasp) {
    int t = threadIdx.x;
    const TF* Wp = (const TF*)gcn_w + (size_t)l * DD * DD;
    const TF* bp = (const TF*)gcn_b + (size_t)l * DD;
    bf16* wo = wtp + (size_t)l * WELEMS;
    for (int idx = t; idx < DD * DD; idx += 256) {
        int k = idx >> 7, n = idx & 127;
        float wv = BETA_F * LD<TF>::f(Wp, idx) + (k == n ? (1.0f - BETA_F) : 0.0f);
        wo[n * WSTRIDE + k] = __float2bfloat16(wv);
    }
    if (t < DD) biasp[l * DD + t] = LD<TF>::f(bp, t);
}

__global__ void k_init(const int* __restrict__ src, const int* __restrict__ dst,
        int* deg_out, int* deg_in, int E, const u16* bn_g_raw, int* flag,
        const void* feat, const void* gcn_w, const void* gcn_b,
        const int* __restrict__ gid, int* gstart, bf16* wtp, float* biasp,
        bf16* hbuf, int N, int CB) {
    int b = blockIdx.x;
    int t = threadIdx.x;
    int bf = (bn_g_raw[0] == 0x3F80) ? 1 : 0;   // local detect (cached read)
    int IC = 2 * CVT_BLOCKS;
    int histTotal = IC + (CB - CVT_BLOCKS);     // CB >= CVT_BLOCKS for this problem
    if (b < histTotal) {
        int role, rid;
        if (b < IC) { role = b & 1; rid = b >> 1; }
        else        { role = 0;     rid = CVT_BLOCKS + (b - IC); }
        if (role == 1) {
            // cvt: feat -> bf16 hbuf
            int total8 = N * DD / 8;
            int i = rid * 256 + t;
            int stride = CVT_BLOCKS * 256;
            uint4* d = (uint4*)hbuf;
            if (bf) {
                const uint4* s = (const uint4*)feat;
                for (; i < total8; i += stride) d[i] = s[i];
            } else {
                const float4* s = (const float4*)feat;
                for (; i < total8; i += stride) {
                    float4 x = s[2 * i], y = s[2 * i + 1];
                    union { uint4 u; bf16 b8[8]; } o;
                    o.b8[0] = __float2bfloat16(x.x); o.b8[1] = __float2bfloat16(x.y);
                    o.b8[2] = __float2bfloat16(x.z); o.b8[3] = __float2bfloat16(x.w);
                    o.b8[4] = __float2bfloat16(y.x); o.b8[5] = __float2bfloat16(y.y);
                    o.b8[6] = __float2bfloat16(y.z); o.b8[7] = __float2bfloat16(y.w);
                    d[i] = o.u;
                }
            }
        } else {
            // degree histogram
            int e = rid * 256 + t;
            if (e < E) {
                atomicAdd(&deg_out[src[e]], 1);
                atomicAdd(&deg_in[dst[e]], 1);
            }
        }
        return;
    }
    b -= histTotal;
    if (b < NL) {
        if (bf) prepw_body<bf16 >(b, gcn_w, gcn_b, wtp, biasp);
        else    prepw_body<float>(b, gcn_w, gcn_b, wtp, biasp);
        return;
    }
    // bounds + flag
    if (t == 0) *flag = bf;
    int g = t;
    if (g <= NG) {
        if (g == NG) gstart[NG] = N;
        else {
            int lo = 0, hi = N;
            while (lo < hi) { int mid = (lo + hi) >> 1; if (gid[mid] < g) lo = mid + 1; else hi = mid; }
            gstart[g] = lo;
        }
    }
}

// ---------------- scan (3-phase) + cursor copy + norm precompute ----------------

__global__ void k_reduce_chunks(const int* __restrict__ deg, int* bsum, int N) {
    __shared__ int lds[256];
    int base = blockIdx.x * 1024;
    int s = 0;
    #pragma unroll
    for (int k = 0; k < 4; ++k) {
        int i = base + threadIdx.x + k * 256;
        if (i < N) s += deg[i];
    }
    lds[threadIdx.x] = s;
    __syncthreads();
    for (int off = 128; off > 0; off >>= 1) {
        if (threadIdx.x < off) lds[threadIdx.x] += lds[threadIdx.x + off];
        __syncthreads();
    }
    if (threadIdx.x == 0) bsum[blockIdx.x] = lds[0];
}

__global__ void k_scan_bsum(int* bsum, int B, int* row_ptr, int N, int E) {
    if (threadIdx.x == 0 && blockIdx.x == 0) {
        int acc = 0;
        for (int i = 0; i < B; ++i) { int v = bsum[i]; bsum[i] = acc; acc += v; }
        row_ptr[N] = E;
    }
}

__global__ void k_scan_chunks(const int* __restrict__ deg_in, const int* __restrict__ deg_out,
                              const int* __restrict__ bsum, int* row_ptr, int* cursor,
                              float* norm_out, float* norm_in, int N) {
    __shared__ int lds[256];
    int t = threadIdx.x;
    int base = blockIdx.x * 1024;
    int vals[4];
    int tsum = 0;
    #pragma unroll
    for (int k = 0; k < 4; ++k) {
        int i = base + t * 4 + k;
        int v = (i < N) ? deg_in[i] : 0;
        vals[k] = tsum;
        tsum += v;
        if (i < N) {
            norm_in[i] = rsqrtf((float)(v > 1 ? v : 1));
            int doo = deg_out[i];
            norm_out[i] = rsqrtf((float)(doo > 1 ? doo : 1));
        }
    }
    lds[t] = tsum;
    __syncthreads();
    for (int off = 1; off < 256; off <<= 1) {
        int add = (t >= off) ? lds[t - off] : 0;
        __syncthreads();
        lds[t] += add;
        __syncthreads();
    }
    int toff = (t > 0 ? lds[t - 1] : 0) + bsum[blockIdx.x];
    #pragma unroll
    for (int k = 0; k < 4; ++k) {
        int i = base + t * 4 + k;
        if (i < N) { int rp = toff + vals[k]; row_ptr[i] = rp; cursor[i] = rp; }
    }
}

__global__ void k_fill_csr(const int* __restrict__ src, const int* __restrict__ dst,
                           int* cursor, int* col, int E) {
    int e = blockIdx.x * blockDim.x + threadIdx.x;
    if (e < E) {
        int p = atomicAdd(&cursor[dst[e]], 1);
        col[p] = src[e];
    }
}

// ---------------- merged pool + gather (both read CLEAN post-BN bf16 h) --------
// blocks [0,poolCnt): pool role — plain per-graph sum of h rows (atomic-free).
// blocks [poolCnt,...): gather role — one wave per node, slot(4) x chunk(16):
// r[node] = 0.9*norm_in*sum(h[src]*norm_out) + 0.1*h[node].
// No BN here: h is already post-BN (materialized by k_gemm_bn phase 2).
__global__ void k_gather_pool(const bf16* __restrict__ h, const int* __restrict__ row_ptr,
        const int* __restrict__ col, const float* __restrict__ norm_out,
        const float* __restrict__ norm_in, const int* __restrict__ gstart,
        float* __restrict__ pooled_l, int poolCnt, bf16* __restrict__ r, int N) {
    int t = threadIdx.x;
    if (blockIdx.x < poolCnt) {
        // ---- pool role ----
        __shared__ float red[16][DD];
        int g = blockIdx.x;
        int rlo = gstart[g], rhi = gstart[g + 1];
        int c = t & 15, rg = t >> 4;
        int d0 = c * 8;
        float acc[8] = {0.f, 0.f, 0.f, 0.f, 0.f, 0.f, 0.f, 0.f};
        for (int i = rlo + rg; i < rhi; i += 16) {
            union { uint4 u; u16 us[8]; } v;
            v.u = *(const uint4*)(h + ((size_t)i << 7) + d0);
            #pragma unroll
            for (int j = 0; j < 8; ++j)
                acc[j] += __uint_as_float((u32)v.us[j] << 16);
        }
        #pragma unroll
        for (int j = 0; j < 8; ++j) red[rg][d0 + j] = acc[j];
        __syncthreads();
        if (t < DD) {
            float s = 0.f;
            #pragma unroll
            for (int k = 0; k < 16; ++k) s += red[k][t];
            pooled_l[g * DD + t] = s;
        }
        return;
    }
    // ---- gather role ----
    int node = (blockIdx.x - poolCnt) * 4 + (t >> 6);
    if (node >= N) return;
    int lane = t & 63;
    int s = lane >> 4, c = lane & 15;
    int d0 = c << 3;
    int beg = row_ptr[node], end = row_ptr[node + 1];
    float acc[8] = {0.f, 0.f, 0.f, 0.f, 0.f, 0.f, 0.f, 0.f};
    for (int e = beg + s; e < end; e += 4) {
        int sn = col[e];
        float no = norm_out[sn];
        union { uint4 u; u16 us[8]; } v;
        v.u = *(const uint4*)(h + ((size_t)sn << 7) + d0);
        #pragma unroll
        for (int j = 0; j < 8; ++j)
            acc[j] += __uint_as_float((u32)v.us[j] << 16) * no;
    }
    #pragma unroll
    for (int j = 0; j < 8; ++j) {
        acc[j] += __shfl_xor(acc[j], 16, 64);
        acc[j] += __shfl_xor(acc[j], 32, 64);
    }
    if (s == 0) {
        float ni = 0.9f * norm_in[node];
        union { uint4 u; u16 us[8]; } sv;
        sv.u = *(const uint4*)(h + ((size_t)node << 7) + d0);
        union { uint4 u; bf16 b8[8]; } o;
        #pragma unroll
        for (int j = 0; j < 8; ++j)
            o.b8[j] = __float2bfloat16(ni * acc[j]
                      + 0.1f * __uint_as_float((u32)sv.us[j] << 16));
        *(uint4*)(r + ((size_t)node << 7) + d0) = o.u;
    }
}

// ---------------- gemm + stats + device barrier + in-place BN/ReLU ------------
// Phase 1 (grid-stride, 2 tiles/block): h = r @ W' + bias (pre-BN, bf16) +
// column sum/sumsq into stats (pad rows masked).
// Barrier: threadfence + agent-scope arrive counter; 391 blocks at
// __launch_bounds__(256,2) -> <=512 co-resident guaranteed, no deadlock.
// Counter is monotonic -> rocprof replay-safe.
// Phase 2: grid-stride in-place BN affine + ReLU at N-rate (gather stays clean).
__global__ __launch_bounds__(256, 2) void k_gemm_bn(
        const bf16* __restrict__ r, const bf16* __restrict__ wt,
        const float* __restrict__ biasf, bf16* __restrict__ h,
        float* __restrict__ stats, const void* bn_g, const void* bn_b, int layer,
        const int* __restrict__ flag, int* counter, int numTiles, int N) {
    __shared__ float sred1[4][128];
    __shared__ float sred2[4][128];
    __shared__ float scs[DD], shs[DD];
    int t = threadIdx.x;
    int w = t >> 6, lane = t & 63;
    int q = lane >> 4, c = lane & 15;

    // ---- phase 1 ----
    for (int tile = blockIdx.x; tile < numTiles; tile += gridDim.x) {
        size_t mbase = (size_t)tile * 128 + (size_t)w * 32;
        f32x4v acc[2][8];
        #pragma unroll
        for (int rt = 0; rt < 2; ++rt)
            #pragma unroll
            for (int ct = 0; ct < 8; ++ct)
                acc[rt][ct] = (f32x4v){0.f, 0.f, 0.f, 0.f};
        #pragma unroll
        for (int ks = 0; ks < 4; ++ks) {
            int k0 = ks * 32 + q * 8;
            union { uint4 u; bf16x8v v; } a0, a1;
            a0.u = *(const uint4*)(r + ((mbase + c) << 7) + k0);
            a1.u = *(const uint4*)(r + ((mbase + 16 + c) << 7) + k0);
            #pragma unroll
            for (int ct = 0; ct < 8; ++ct) {
                union { uint4 u; bf16x8v v; } b;
                b.u = *(const uint4*)(wt + (size_t)(ct * 16 + c) * WSTRIDE + k0);
                acc[0][ct] = __builtin_amdgcn_mfma_f32_16x16x32_bf16(a0.v, b.v, acc[0][ct], 0, 0, 0);
                acc[1][ct] = __builtin_amdgcn_mfma_f32_16x16x32_bf16(a1.v, b.v, acc[1][ct], 0, 0, 0);
            }
        }
        // epilogue: C layout col = lane&15, row = quad*4 + reg  [m89-verified]
        float s1[8] = {0.f, 0.f, 0.f, 0.f, 0.f, 0.f, 0.f, 0.f};
        float s2[8] = {0.f, 0.f, 0.f, 0.f, 0.f, 0.f, 0.f, 0.f};
        #pragma unroll
        for (int ct = 0; ct < 8; ++ct) {
            int coln = ct * 16 + c;
            float bs = biasf[coln];
            #pragma unroll
            for (int rt = 0; rt < 2; ++rt) {
                size_t mrow = mbase + rt * 16 + q * 4;
                #pragma unroll
                for (int reg = 0; reg < 4; ++reg) {
                    size_t row = mrow + reg;
                    float v = acc[rt][ct][reg] + bs;
                    if (row < (size_t)N) {
                        h[(row << 7) + coln] = __float2bfloat16(v);
                        s1[ct] += v;
                        s2[ct] += v * v;
                    }
                }
            }
        }
        #pragma unroll
        for (int j = 0; j < 8; ++j) {
            s1[j] += __shfl_xor(s1[j], 16, 64); s1[j] += __shfl_xor(s1[j], 32, 64);
            s2[j] += __shfl_xor(s2[j], 16, 64); s2[j] += __shfl_xor(s2[j], 32, 64);
        }
        if (q == 0) {
            #pragma unroll
            for (int ct = 0; ct < 8; ++ct) {
                sred1[w][ct * 16 + c] = s1[ct];
                sred2[w][ct * 16 + c] = s2[ct];
            }
        }
        __syncthreads();
        if (t < DD) {
            float a1 = sred1[0][t] + sred1[1][t] + sred1[2][t] + sred1[3][t];
            float a2 = sred2[0][t] + sred2[1][t] + sred2[2][t] + sred2[3][t];
            atomicAdd(&stats[t], a1);
            atomicAdd(&stats[DD + t], a2);
        }
        __syncthreads();   // sred reuse guard for next tile
    }

    // ---- device-wide barrier (arrive + spin) ----
    __syncthreads();
    if (t == 0) {
        __threadfence();
        __hip_atomic_fetch_add(counter, 1, __ATOMIC_ACQ_REL, __HIP_MEMORY_SCOPE_AGENT);
        while (__hip_atomic_load(counter, __ATOMIC_ACQUIRE, __HIP_MEMORY_SCOPE_AGENT)
               < (int)gridDim.x) {
            __builtin_amdgcn_s_sleep(2);
        }
        __threadfence();
    }
    __syncthreads();

    // ---- phase 2: BN affine + ReLU in place at N-rate ----
    int bf = *flag;
    if (t < DD) {
        size_t esz = bf ? 2u : 4u;
        const char* gp = (const char*)bn_g + (size_t)layer * DD * esz;
        const char* bp = (const char*)bn_b + (size_t)layer * DD * esz;
        float gv = bf ? LD<bf16>::f(gp, t) : LD<float>::f(gp, t);
        float bv = bf ? LD<bf16>::f(bp, t) : LD<float>::f(bp, t);
        float invN = 1.0f / (float)N;
        float mu = stats[t] * invN;
        float var = fmaxf(stats[DD + t] * invN - mu * mu, 0.f);
        float sc = rsqrtf(var + BN_EPS_F) * gv;
        scs[t] = sc;
        shs[t] = bv - mu * sc;
    }
    __syncthreads();
    int total8 = N * 16;                      // uint4 count (N * 128 / 8)
    int stride = gridDim.x * 256;             // multiple of 16 -> d0 per-thread const
    int i0 = blockIdx.x * 256 + t;
    int d0 = (i0 & 15) * 8;
    float rsc[8], rsh[8];
    #pragma unroll
    for (int j = 0; j < 8; ++j) { rsc[j] = scs[d0 + j]; rsh[j] = shs[d0 + j]; }
    for (int i = i0; i < total8; i += stride) {
        union { uint4 u; u16 us[8]; } v;
        v.u = ((const uint4*)h)[i];
        union { uint4 u; bf16 b8[8]; } o;
        #pragma unroll
        for (int j = 0; j < 8; ++j) {
            float f = __uint_as_float((u32)v.us[j] << 16) * rsc[j] + rsh[j];
            o.b8[j] = __float2bfloat16(fmaxf(f, 0.f));
        }
        ((uint4*)h)[i] = o.u;
    }
}

// ---------------- head (parallelized over 128 dims) ----------------

template<typename TF>
__device__ __forceinline__ void head_body(const float* __restrict__ pooled,
        const void* lin_w, const void* lin_b, void* out) {
    int g = blockIdx.x;   // 200
    int t = threadIdx.x;  // 128
    __shared__ float red[128 * 10];
    __shared__ float scv[10];
    __shared__ float lse;
    float part[10] = {0.f, 0.f, 0.f, 0.f, 0.f, 0.f, 0.f, 0.f, 0.f, 0.f};
    float mp = 0.f;
    for (int l = 0; l < NL + 1; ++l) {
        float pl = pooled[(size_t)(l * NG + g) * DD + t];
        if (l > 0) mp += pl;
        #pragma unroll
        for (int o = 0; o < 10; ++o)
            part[o] += pl * LD<TF>::f(lin_w, (size_t)l * DD * 10 + (size_t)t * 10 + o);
    }
    #pragma unroll
    for (int o = 0; o < 10; ++o) red[t * 10 + o] = part[o];
    __syncthreads();
    for (int off = 64; off >= 1; off >>= 1) {
        if (t < off) {
            #pragma unroll
            for (int o = 0; o < 10; ++o) red[t * 10 + o] += red[(t + off) * 10 + o];
        }
        __syncthreads();
    }
    if (t < 10) {
        float s = red[t];
        for (int l = 0; l < NL + 1; ++l) s += LD<TF>::f(lin_b, l * 10 + t);
        scv[t] = s;
    }
    __syncthreads();
    if (t == 0) {
        float m = scv[0];
        for (int o = 1; o < 10; ++o) m = fmaxf(m, scv[o]);
        float su = 0.f;
        for (int o = 0; o < 10; ++o) su += expf(scv[o] - m);
        lse = m + logf(su);
    }
    __syncthreads();
    if (t < 10) ST<TF>::s(out, g * 10 + t, scv[t] - lse);
    ST<TF>::s(out, NG * 10 + (size_t)g * DD + t, mp * 0.2f);
}

__global__ void k_head(const float* __restrict__ pooled, const int* __restrict__ flag,
        const void* lin_w, const void* lin_b, void* out) {
    if (*flag) head_body<bf16 >(pooled, lin_w, lin_b, out);
    else       head_body<float>(pooled, lin_w, lin_b, out);
}

// ---------------- launch ----------------

extern "C" void kernel_launch(void* const* d_in, const int* in_sizes, int n_in,
                              void* d_out, int out_size, void* d_ws, size_t ws_size,
                              hipStream_t stream) {
    const void* feat  = d_in[0];
    const int*  src   = (const int*)d_in[1];
    const int*  dst   = (const int*)d_in[2];
    const int*  gid   = (const int*)d_in[3];
    const void* gcn_w = d_in[4];
    const void* gcn_b = d_in[5];
    const void* bn_g  = d_in[6];
    const void* bn_b  = d_in[7];
    const void* lin_w = d_in[8];
    const void* lin_b = d_in[9];
    const int N = in_sizes[0] / DD;   // 100000
    const int E = in_sizes[1];        // 600000
    const int Mpad = ((N + 127) / 128) * 128;
    const int numTiles = Mpad / 128;                 // 782
    const int GBLK = (numTiles + 1) / 2;             // 391 <= 512 co-resident

    char* wsb = (char*)d_ws;
    size_t off = 0;
    auto carve = [&](size_t bytes) -> void* {
        void* p = wsb + off;
        off = (off + bytes + 255) & ~(size_t)255;
        return p;
    };
    int*   flag     = (int*)carve(4);
    // zeroed region: deg_out .. counters (one memset)
    int*   deg_out  = (int*)carve((size_t)N * 4);
    int*   deg_in   = (int*)carve((size_t)N * 4);
    float* statsAll = (float*)carve((size_t)NL * 2 * DD * 4);
    int*   counters = (int*)carve(16 * 4);
    // un-zeroed scratch
    int*   row_ptr  = (int*)carve((size_t)(N + 1) * 4);
    int*   cursor   = (int*)carve((size_t)N * 4);
    int*   col      = (int*)carve((size_t)E * 4);
    int*   bsum     = (int*)carve(1024 * 4);
    int*   gstart   = (int*)carve((size_t)(NG + 1) * 4);
    float* norm_out = (float*)carve((size_t)N * 4);
    float* norm_in  = (float*)carve((size_t)N * 4);
    bf16*  wtp      = (bf16*)carve((size_t)NL * WELEMS * 2);
    float* biasp    = (float*)carve((size_t)NL * DD * 4);
    float* pooled   = (float*)carve((size_t)(NL + 1) * NG * DD * 4);
    bf16*  hA       = (bf16*)carve((size_t)Mpad * DD * 2);
    bf16*  hB       = (bf16*)carve((size_t)Mpad * DD * 2);
    bf16*  rbuf     = (bf16*)carve((size_t)Mpad * DD * 2);

    if (off > ws_size) return;   // guard: leave d_out zeroed (distinguishable)

    hipMemsetAsync(deg_out, 0,
                   (size_t)((char*)counters - (char*)deg_out) + 16 * 4, stream);

    const int CB = (E + 255) / 256;
    k_init<<<CVT_BLOCKS + CB + NL + 1, 256, 0, stream>>>(
        src, dst, deg_out, deg_in, E, (const u16*)bn_g, flag,
        feat, gcn_w, gcn_b, gid, gstart, wtp, biasp, hA, N, CB);

    int B = (N + 1023) / 1024;
    k_reduce_chunks<<<B, 256, 0, stream>>>(deg_in, bsum, N);
    k_scan_bsum<<<1, 64, 0, stream>>>(bsum, B, row_ptr, N, E);
    k_scan_chunks<<<B, 256, 0, stream>>>(deg_in, deg_out, bsum, row_ptr, cursor,
                                         norm_out, norm_in, N);
    k_fill_csr<<<(E + 255) / 256, 256, 0, stream>>>(src, dst, cursor, col, E);

    const int GB = (N + 3) / 4;   // gather blocks
    bf16* bufs[2] = { hA, hB };
    for (int l = 0; l < NL; ++l) {
        bf16* hin  = bufs[l & 1];
        bf16* hout = bufs[(l + 1) & 1];
        // pool role pools hidden_rep[l] (post-BN h, or cvt(feat) for l==0) into pooled[l]
        k_gather_pool<<<NG + GB, 256, 0, stream>>>(
            hin, row_ptr, col, norm_out, norm_in, gstart,
            pooled + (size_t)l * NG * DD, NG, rbuf, N);
        k_gemm_bn<<<GBLK, 256, 0, stream>>>(
            rbuf, wtp + (size_t)l * WELEMS, biasp + (size_t)l * DD, hout,
            statsAll + (size_t)l * 2 * DD, bn_g, bn_b, l, flag,
            counters + l, numTiles, N);
    }

    // final pool: hidden_rep[NL] = post-BN h from layer NL-1
    k_gather_pool<<<NG, 256, 0, stream>>>(
        bufs[NL & 1], row_ptr, col, norm_out, norm_in, gstart,
        pooled + (size_t)NL * NG * DD, NG, rbuf, N);

    k_head<<<NG, DD, 0, stream>>>(pooled, flag, lin_w, lin_b, d_out);
}

// Round 12
// 673.763 us; speedup vs baseline: 1.4771x; 1.4771x over previous
//
#include <hip/hip_runtime.h>
#include <hip/hip_bf16.h>

typedef __hip_bfloat16 bf16;
typedef unsigned short u16;
typedef unsigned int u32;

#define DD 128           // feature dim
#define NG 200           // graphs
#define NL 5             // GCN layers
#define BETA_F 0.007782140442054161f   // log(1/128 + 1)
#define BN_EPS_F 1e-5f
#define WSTRIDE 136      // padded W' row stride (bf16 elems); 128x136 per layer
#define WELEMS (DD * WSTRIDE)
#define CVT_BLOCKS 1024

typedef __attribute__((ext_vector_type(8))) short bf16x8v;
typedef __attribute__((ext_vector_type(4))) float f32x4v;

// ---- dtype-generic load/store helpers (flag-selected, wave-uniform) ----

template<typename T> struct LD;
template<> struct LD<float> {
    static __device__ __forceinline__ float f(const void* p, size_t i) {
        return ((const float*)p)[i];
    }
};
template<> struct LD<bf16> {
    static __device__ __forceinline__ float f(const void* p, size_t i) {
        return __bfloat162float(((const bf16*)p)[i]);
    }
};
template<typename T> struct ST;
template<> struct ST<float> {
    static __device__ __forceinline__ void s(void* p, size_t i, float v) {
        ((float*)p)[i] = v;
    }
};
template<> struct ST<bf16> {
    static __device__ __forceinline__ void s(void* p, size_t i, float v) {
        ((bf16*)p)[i] = __float2bfloat16(v);
    }
};

// ---------------- k_init: INTERLEAVED cvt+count, then prepw, bounds ------------
// blocks [0, 2*CVT): alternate count(b&1==0)/cvt(b&1==1) so the atomic-bound
// histogram and the BW-bound cvt co-reside per CU (overlap: time ~ max not sum).
// blocks [2*CVT, CVT+CB): remaining count blocks.
// next NL: prepw (W' = beta*W + (1-beta)*I, padded n-major, + fp32 bias)
// last 1: bounds (graph start offsets; gid sorted) + flag write
template<typename TF>
__device__ __forceinline__ void prepw_body(int l, const void* gcn_w, const void* gcn_b,
        bf16* __restrict__ wtp, float* __restrict__ biasp) {
    int t = threadIdx.x;
    const TF* Wp = (const TF*)gcn_w + (size_t)l * DD * DD;
    const TF* bp = (const TF*)gcn_b + (size_t)l * DD;
    bf16* wo = wtp + (size_t)l * WELEMS;
    for (int idx = t; idx < DD * DD; idx += 256) {
        int k = idx >> 7, n = idx & 127;
        float wv = BETA_F * LD<TF>::f(Wp, idx) + (k == n ? (1.0f - BETA_F) : 0.0f);
        wo[n * WSTRIDE + k] = __float2bfloat16(wv);
    }
    if (t < DD) biasp[l * DD + t] = LD<TF>::f(bp, t);
}

__global__ void k_init(const int* __restrict__ src, const int* __restrict__ dst,
        int* deg_out, int* deg_in, int E, const u16* bn_g_raw, int* flag,
        const void* feat, const void* gcn_w, const void* gcn_b,
        const int* __restrict__ gid, int* gstart, bf16* wtp, float* biasp,
        bf16* hbuf, int N, int CB) {
    int b = blockIdx.x;
    int t = threadIdx.x;
    int bf = (bn_g_raw[0] == 0x3F80) ? 1 : 0;   // local detect (cached read)
    int IC = 2 * CVT_BLOCKS;
    int histTotal = IC + (CB - CVT_BLOCKS);     // CB >= CVT_BLOCKS for this problem
    if (b < histTotal) {
        int role, rid;
        if (b < IC) { role = b & 1; rid = b >> 1; }
        else        { role = 0;     rid = CVT_BLOCKS + (b - IC); }
        if (role == 1) {
            // cvt: feat -> bf16 hbuf
            int total8 = N * DD / 8;
            int i = rid * 256 + t;
            int stride = CVT_BLOCKS * 256;
            uint4* d = (uint4*)hbuf;
            if (bf) {
                const uint4* s = (const uint4*)feat;
                for (; i < total8; i += stride) d[i] = s[i];
            } else {
                const float4* s = (const float4*)feat;
                for (; i < total8; i += stride) {
                    float4 x = s[2 * i], y = s[2 * i + 1];
                    union { uint4 u; bf16 b8[8]; } o;
                    o.b8[0] = __float2bfloat16(x.x); o.b8[1] = __float2bfloat16(x.y);
                    o.b8[2] = __float2bfloat16(x.z); o.b8[3] = __float2bfloat16(x.w);
                    o.b8[4] = __float2bfloat16(y.x); o.b8[5] = __float2bfloat16(y.y);
                    o.b8[6] = __float2bfloat16(y.z); o.b8[7] = __float2bfloat16(y.w);
                    d[i] = o.u;
                }
            }
        } else {
            // degree histogram
            int e = rid * 256 + t;
            if (e < E) {
                atomicAdd(&deg_out[src[e]], 1);
                atomicAdd(&deg_in[dst[e]], 1);
            }
        }
        return;
    }
    b -= histTotal;
    if (b < NL) {
        if (bf) prepw_body<bf16 >(b, gcn_w, gcn_b, wtp, biasp);
        else    prepw_body<float>(b, gcn_w, gcn_b, wtp, biasp);
        return;
    }
    // bounds + flag
    if (t == 0) *flag = bf;
    int g = t;
    if (g <= NG) {
        if (g == NG) gstart[NG] = N;
        else {
            int lo = 0, hi = N;
            while (lo < hi) { int mid = (lo + hi) >> 1; if (gid[mid] < g) lo = mid + 1; else hi = mid; }
            gstart[g] = lo;
        }
    }
}

// ---------------- scan (3-phase) + cursor copy + norm precompute ----------------

__global__ void k_reduce_chunks(const int* __restrict__ deg, int* bsum, int N) {
    __shared__ int lds[256];
    int base = blockIdx.x * 1024;
    int s = 0;
    #pragma unroll
    for (int k = 0; k < 4; ++k) {
        int i = base + threadIdx.x + k * 256;
        if (i < N) s += deg[i];
    }
    lds[threadIdx.x] = s;
    __syncthreads();
    for (int off = 128; off > 0; off >>= 1) {
        if (threadIdx.x < off) lds[threadIdx.x] += lds[threadIdx.x + off];
        __syncthreads();
    }
    if (threadIdx.x == 0) bsum[blockIdx.x] = lds[0];
}

__global__ void k_scan_bsum(int* bsum, int B, int* row_ptr, int N, int E) {
    if (threadIdx.x == 0 && blockIdx.x == 0) {
        int acc = 0;
        for (int i = 0; i < B; ++i) { int v = bsum[i]; bsum[i] = acc; acc += v; }
        row_ptr[N] = E;
    }
}

__global__ void k_scan_chunks(const int* __restrict__ deg_in, const int* __restrict__ deg_out,
                              const int* __restrict__ bsum, int* row_ptr, int* cursor,
                              float* norm_out, float* norm_in, int N) {
    __shared__ int lds[256];
    int t = threadIdx.x;
    int base = blockIdx.x * 1024;
    int vals[4];
    int tsum = 0;
    #pragma unroll
    for (int k = 0; k < 4; ++k) {
        int i = base + t * 4 + k;
        int v = (i < N) ? deg_in[i] : 0;
        vals[k] = tsum;
        tsum += v;
        if (i < N) {
            norm_in[i] = rsqrtf((float)(v > 1 ? v : 1));
            int doo = deg_out[i];
            norm_out[i] = rsqrtf((float)(doo > 1 ? doo : 1));
        }
    }
    lds[t] = tsum;
    __syncthreads();
    for (int off = 1; off < 256; off <<= 1) {
        int add = (t >= off) ? lds[t - off] : 0;
        __syncthreads();
        lds[t] += add;
        __syncthreads();
    }
    int toff = (t > 0 ? lds[t - 1] : 0) + bsum[blockIdx.x];
    #pragma unroll
    for (int k = 0; k < 4; ++k) {
        int i = base + t * 4 + k;
        if (i < N) { int rp = toff + vals[k]; row_ptr[i] = rp; cursor[i] = rp; }
    }
}

__global__ void k_fill_csr(const int* __restrict__ src, const int* __restrict__ dst,
                           int* cursor, int* col, int E) {
    int e = blockIdx.x * blockDim.x + threadIdx.x;
    if (e < E) {
        int p = atomicAdd(&cursor[dst[e]], 1);
        col[p] = src[e];
    }
}

// ---------------- merged pool(hidden_rep[l]) + gather (BN-affine on the fly) ---
// BN scale/shift computed ONCE per block into LDS.
// blocks [0,poolCnt): pool role — pools affine(h) into pooled_l (atomic-free).
// blocks [poolCnt,...): gather role — one wave per node, slot(4) x chunk(16),
// r[node] = 0.9*norm_in*sum(affine(h[src])*norm_out) + 0.1*affine(h[node]).
template<typename TF>
__device__ __forceinline__ void gp_body(const bf16* __restrict__ h,
        const int* __restrict__ row_ptr, const int* __restrict__ col,
        const float* __restrict__ norm_out, const float* __restrict__ norm_in,
        const float* __restrict__ stats, const void* gamma, const void* beta,
        int apply, const int* __restrict__ gstart, float* __restrict__ pooled_l,
        int poolCnt, bf16* __restrict__ r, int N) {
    __shared__ float s_sc[DD], s_sh[DD];
    int t = threadIdx.x;
    if (t < DD) {
        float sc = 1.f, sh = 0.f;
        if (apply) {
            float invN = 1.0f / (float)N;
            float mu = stats[t] * invN;
            float var = fmaxf(stats[DD + t] * invN - mu * mu, 0.f);
            sc = rsqrtf(var + BN_EPS_F) * LD<TF>::f(gamma, t);
            sh = LD<TF>::f(beta, t) - mu * sc;
        }
        s_sc[t] = sc; s_sh[t] = sh;
    }
    __syncthreads();
    float lo = apply ? 0.f : -__builtin_inff();

    if (blockIdx.x < poolCnt) {
        // ---- pool role ----
        __shared__ float red[16][DD];
        int g = blockIdx.x;
        int rlo = gstart[g], rhi = gstart[g + 1];
        int c = t & 15, rg = t >> 4;
        int d0 = c * 8;
        float sc8[8], sh8[8];
        #pragma unroll
        for (int j = 0; j < 8; ++j) { sc8[j] = s_sc[d0 + j]; sh8[j] = s_sh[d0 + j]; }
        float acc[8] = {0.f, 0.f, 0.f, 0.f, 0.f, 0.f, 0.f, 0.f};
        for (int i = rlo + rg; i < rhi; i += 16) {
            union { uint4 u; u16 us[8]; } v;
            v.u = *(const uint4*)(h + ((size_t)i << 7) + d0);
            #pragma unroll
            for (int j = 0; j < 8; ++j) {
                float f = __uint_as_float((u32)v.us[j] << 16) * sc8[j] + sh8[j];
                acc[j] += fmaxf(f, lo);
            }
        }
        #pragma unroll
        for (int j = 0; j < 8; ++j) red[rg][d0 + j] = acc[j];
        __syncthreads();
        if (t < DD) {
            float s = 0.f;
            #pragma unroll
            for (int k = 0; k < 16; ++k) s += red[k][t];
            pooled_l[g * DD + t] = s;
        }
        return;
    }

    // ---- gather role ----
    int node = (blockIdx.x - poolCnt) * 4 + (t >> 6);
    if (node >= N) return;
    int lane = t & 63;
    int s = lane >> 4, c = lane & 15;
    int d0 = c << 3;
    float sc8[8], sh8[8];
    #pragma unroll
    for (int j = 0; j < 8; ++j) { sc8[j] = s_sc[d0 + j]; sh8[j] = s_sh[d0 + j]; }
    int beg = row_ptr[node], end = row_ptr[node + 1];
    float acc[8] = {0.f, 0.f, 0.f, 0.f, 0.f, 0.f, 0.f, 0.f};
    for (int e = beg + s; e < end; e += 4) {
        int sn = col[e];
        float no = norm_out[sn];
        union { uint4 u; u16 us[8]; } v;
        v.u = *(const uint4*)(h + ((size_t)sn << 7) + d0);
        #pragma unroll
        for (int j = 0; j < 8; ++j) {
            float f = __uint_as_float((u32)v.us[j] << 16) * sc8[j] + sh8[j];
            acc[j] += fmaxf(f, lo) * no;
        }
    }
    #pragma unroll
    for (int j = 0; j < 8; ++j) {
        acc[j] += __shfl_xor(acc[j], 16, 64);
        acc[j] += __shfl_xor(acc[j], 32, 64);
    }
    if (s == 0) {
        float ni = 0.9f * norm_in[node];
        union { uint4 u; u16 us[8]; } sv;
        sv.u = *(const uint4*)(h + ((size_t)node << 7) + d0);
        union { uint4 u; bf16 b8[8]; } o;
        #pragma unroll
        for (int j = 0; j < 8; ++j) {
            float f = __uint_as_float((u32)sv.us[j] << 16) * sc8[j] + sh8[j];
            f = fmaxf(f, lo);
            o.b8[j] = __float2bfloat16(ni * acc[j] + 0.1f * f);
        }
        *(uint4*)(r + ((size_t)node << 7) + d0) = o.u;
    }
}

__global__ void k_gather_pool(const bf16* __restrict__ h, const int* __restrict__ row_ptr,
        const int* __restrict__ col, const float* __restrict__ norm_out,
        const float* __restrict__ norm_in, const float* __restrict__ stats,
        const void* bn_g, const void* bn_b, int laff, int apply,
        const int* __restrict__ gstart, float* __restrict__ pooled_l, int poolCnt,
        const int* __restrict__ flag, bf16* __restrict__ r, int N) {
    int bf = *flag;
    size_t esz = bf ? 2u : 4u;
    const char* gp = (const char*)bn_g + (size_t)laff * DD * esz;
    const char* bp = (const char*)bn_b + (size_t)laff * DD * esz;
    if (bf) gp_body<bf16 >(h, row_ptr, col, norm_out, norm_in, stats, gp, bp, apply,
                           gstart, pooled_l, poolCnt, r, N);
    else    gp_body<float>(h, row_ptr, col, norm_out, norm_in, stats, gp, bp, apply,
                           gstart, pooled_l, poolCnt, r, N);
}

// ---------------- projection GEMM + fused column stats ----------------
// h_out = r @ W' + bias (pre-BN). B-frags read DIRECTLY from the L2-hot prepped
// W' (139 KB total; no LDS staging -> only 4 KB LDS, higher occupancy).
// Accumulates per-column sum/sumsq of the fp32 output into stats (pad rows masked).
__global__ void k_gemm(const bf16* __restrict__ r, const bf16* __restrict__ wt,
                       const float* __restrict__ biasf, bf16* __restrict__ h_out,
                       float* __restrict__ stats, int N) {
    __shared__ float sred1[4][128];
    __shared__ float sred2[4][128];
    int t = threadIdx.x;
    int w = t >> 6, lane = t & 63;
    int q = lane >> 4, c = lane & 15;
    size_t mbase = (size_t)blockIdx.x * 128 + (size_t)w * 32;
    f32x4v acc[2][8];
    #pragma unroll
    for (int rt = 0; rt < 2; ++rt)
        #pragma unroll
        for (int ct = 0; ct < 8; ++ct)
            acc[rt][ct] = (f32x4v){0.f, 0.f, 0.f, 0.f};
    #pragma unroll
    for (int ks = 0; ks < 4; ++ks) {
        int k0 = ks * 32 + q * 8;
        union { uint4 u; bf16x8v v; } a0, a1;
        a0.u = *(const uint4*)(r + ((mbase + c) << 7) + k0);
        a1.u = *(const uint4*)(r + ((mbase + 16 + c) << 7) + k0);
        #pragma unroll
        for (int ct = 0; ct < 8; ++ct) {
            union { uint4 u; bf16x8v v; } b;
            b.u = *(const uint4*)(wt + (size_t)(ct * 16 + c) * WSTRIDE + k0);
            acc[0][ct] = __builtin_amdgcn_mfma_f32_16x16x32_bf16(a0.v, b.v, acc[0][ct], 0, 0, 0);
            acc[1][ct] = __builtin_amdgcn_mfma_f32_16x16x32_bf16(a1.v, b.v, acc[1][ct], 0, 0, 0);
        }
    }
    // epilogue: C layout col = lane&15, row = quad*4 + reg  [m89-verified]
    float s1[8] = {0.f, 0.f, 0.f, 0.f, 0.f, 0.f, 0.f, 0.f};
    float s2[8] = {0.f, 0.f, 0.f, 0.f, 0.f, 0.f, 0.f, 0.f};
    #pragma unroll
    for (int ct = 0; ct < 8; ++ct) {
        int coln = ct * 16 + c;
        float bs = biasf[coln];
        #pragma unroll
        for (int rt = 0; rt < 2; ++rt) {
            size_t mrow = mbase + rt * 16 + q * 4;
            #pragma unroll
            for (int reg = 0; reg < 4; ++reg) {
                size_t row = mrow + reg;
                float v = acc[rt][ct][reg] + bs;
                if (row < (size_t)N) {
                    h_out[(row << 7) + coln] = __float2bfloat16(v);
                    s1[ct] += v;
                    s2[ct] += v * v;
                }
            }
        }
    }
    #pragma unroll
    for (int j = 0; j < 8; ++j) {
        s1[j] += __shfl_xor(s1[j], 16, 64); s1[j] += __shfl_xor(s1[j], 32, 64);
        s2[j] += __shfl_xor(s2[j], 16, 64); s2[j] += __shfl_xor(s2[j], 32, 64);
    }
    if (q == 0) {
        #pragma unroll
        for (int ct = 0; ct < 8; ++ct) {
            sred1[w][ct * 16 + c] = s1[ct];
            sred2[w][ct * 16 + c] = s2[ct];
        }
    }
    __syncthreads();
    if (t < DD) {
        float a1 = sred1[0][t] + sred1[1][t] + sred1[2][t] + sred1[3][t];
        float a2 = sred2[0][t] + sred2[1][t] + sred2[2][t] + sred2[3][t];
        atomicAdd(&stats[t], a1);
        atomicAdd(&stats[DD + t], a2);
    }
}

// ---------------- head (parallelized over 128 dims) ----------------

template<typename TF>
__device__ __forceinline__ void head_body(const float* __restrict__ pooled,
        const void* lin_w, const void* lin_b, void* out) {
    int g = blockIdx.x;   // 200
    int t = threadIdx.x;  // 128
    __shared__ float red[128 * 10];
    __shared__ float scv[10];
    __shared__ float lse;
    float part[10] = {0.f, 0.f, 0.f, 0.f, 0.f, 0.f, 0.f, 0.f, 0.f, 0.f};
    float mp = 0.f;
    for (int l = 0; l < NL + 1; ++l) {
        float pl = pooled[(size_t)(l * NG + g) * DD + t];
        if (l > 0) mp += pl;
        #pragma unroll
        for (int o = 0; o < 10; ++o)
            part[o] += pl * LD<TF>::f(lin_w, (size_t)l * DD * 10 + (size_t)t * 10 + o);
    }
    #pragma unroll
    for (int o = 0; o < 10; ++o) red[t * 10 + o] = part[o];
    __syncthreads();
    for (int off = 64; off >= 1; off >>= 1) {
        if (t < off) {
            #pragma unroll
            for (int o = 0; o < 10; ++o) red[t * 10 + o] += red[(t + off) * 10 + o];
        }
        __syncthreads();
    }
    if (t < 10) {
        float s = red[t];
        for (int l = 0; l < NL + 1; ++l) s += LD<TF>::f(lin_b, l * 10 + t);
        scv[t] = s;
    }
    __syncthreads();
    if (t == 0) {
        float m = scv[0];
        for (int o = 1; o < 10; ++o) m = fmaxf(m, scv[o]);
        float su = 0.f;
        for (int o = 0; o < 10; ++o) su += expf(scv[o] - m);
        lse = m + logf(su);
    }
    __syncthreads();
    if (t < 10) ST<TF>::s(out, g * 10 + t, scv[t] - lse);
    ST<TF>::s(out, NG * 10 + (size_t)g * DD + t, mp * 0.2f);
}

__global__ void k_head(const float* __restrict__ pooled, const int* __restrict__ flag,
        const void* lin_w, const void* lin_b, void* out) {
    if (*flag) head_body<bf16 >(pooled, lin_w, lin_b, out);
    else       head_body<float>(pooled, lin_w, lin_b, out);
}

// ---------------- launch ----------------

extern "C" void kernel_launch(void* const* d_in, const int* in_sizes, int n_in,
                              void* d_out, int out_size, void* d_ws, size_t ws_size,
                              hipStream_t stream) {
    const void* feat  = d_in[0];
    const int*  src   = (const int*)d_in[1];
    const int*  dst   = (const int*)d_in[2];
    const int*  gid   = (const int*)d_in[3];
    const void* gcn_w = d_in[4];
    const void* gcn_b = d_in[5];
    const void* bn_g  = d_in[6];
    const void* bn_b  = d_in[7];
    const void* lin_w = d_in[8];
    const void* lin_b = d_in[9];
    const int N = in_sizes[0] / DD;   // 100000
    const int E = in_sizes[1];        // 600000
    const int Mpad = ((N + 127) / 128) * 128;

    char* wsb = (char*)d_ws;
    size_t off = 0;
    auto carve = [&](size_t bytes) -> void* {
        void* p = wsb + off;
        off = (off + bytes + 255) & ~(size_t)255;
        return p;
    };
    int*   flag     = (int*)carve(4);
    // zeroed region: deg_out .. statsAll (one memset)
    int*   deg_out  = (int*)carve((size_t)N * 4);
    int*   deg_in   = (int*)carve((size_t)N * 4);
    float* statsAll = (float*)carve((size_t)NL * 2 * DD * 4);
    // un-zeroed scratch
    int*   row_ptr  = (int*)carve((size_t)(N + 1) * 4);
    int*   cursor   = (int*)carve((size_t)N * 4);
    int*   col      = (int*)carve((size_t)E * 4);
    int*   bsum     = (int*)carve(1024 * 4);
    int*   gstart   = (int*)carve((size_t)(NG + 1) * 4);
    float* norm_out = (float*)carve((size_t)N * 4);
    float* norm_in  = (float*)carve((size_t)N * 4);
    bf16*  wtp      = (bf16*)carve((size_t)NL * WELEMS * 2);
    float* biasp    = (float*)carve((size_t)NL * DD * 4);
    float* pooled   = (float*)carve((size_t)(NL + 1) * NG * DD * 4);
    bf16*  hA       = (bf16*)carve((size_t)Mpad * DD * 2);
    bf16*  hB       = (bf16*)carve((size_t)Mpad * DD * 2);
    bf16*  rbuf     = (bf16*)carve((size_t)Mpad * DD * 2);

    if (off > ws_size) return;   // guard: leave d_out zeroed (distinguishable)

    hipMemsetAsync(deg_out, 0,
                   (size_t)((char*)statsAll - (char*)deg_out) + (size_t)NL * 2 * DD * 4,
                   stream);

    const int CB = (E + 255) / 256;
    k_init<<<CVT_BLOCKS + CB + NL + 1, 256, 0, stream>>>(
        src, dst, deg_out, deg_in, E, (const u16*)bn_g, flag,
        feat, gcn_w, gcn_b, gid, gstart, wtp, biasp, hA, N, CB);

    int B = (N + 1023) / 1024;
    k_reduce_chunks<<<B, 256, 0, stream>>>(deg_in, bsum, N);
    k_scan_bsum<<<1, 64, 0, stream>>>(bsum, B, row_ptr, N, E);
    k_scan_chunks<<<B, 256, 0, stream>>>(deg_in, deg_out, bsum, row_ptr, cursor,
                                         norm_out, norm_in, N);
    k_fill_csr<<<(E + 255) / 256, 256, 0, stream>>>(src, dst, cursor, col, E);

    const int GB = (N + 3) / 4;   // gather blocks
    bf16* bufs[2] = { hA, hB };
    for (int l = 0; l < NL; ++l) {
        bf16* hin  = bufs[l & 1];
        bf16* hout = bufs[(l + 1) & 1];
        float* stats  = statsAll + (size_t)l * 2 * DD;                      // written by gemm[l]
        float* statsP = statsAll + (size_t)(l > 0 ? l - 1 : 0) * 2 * DD;    // prev layer's
        // pool role pools hidden_rep[l] (= affine(hin); raw h0 for l==0) into pooled[l]
        k_gather_pool<<<NG + GB, 256, 0, stream>>>(
            hin, row_ptr, col, norm_out, norm_in, statsP, bn_g, bn_b,
            l > 0 ? l - 1 : 0, l > 0 ? 1 : 0, gstart,
            pooled + (size_t)l * NG * DD, NG, flag, rbuf, N);
        k_gemm<<<Mpad / 128, 256, 0, stream>>>(rbuf, wtp + (size_t)l * WELEMS,
                                               biasp + (size_t)l * DD, hout, stats, N);
    }

    // final pool: hidden_rep[NL] from gemm[NL-1] output (stats[NL-1], bn[NL-1])
    k_gather_pool<<<NG, 256, 0, stream>>>(
        bufs[NL & 1], row_ptr, col, norm_out, norm_in,
        statsAll + (size_t)(NL - 1) * 2 * DD, bn_g, bn_b, NL - 1, 1, gstart,
        pooled + (size_t)NL * NG * DD, NG, flag, rbuf, N);

    k_head<<<NG, DD, 0, stream>>>(pooled, flag, lin_w, lin_b, d_out);
}

// Round 13
// 627.131 us; speedup vs baseline: 1.5869x; 1.0744x over previous
//
#include <hip/hip_runtime.h>
#include <hip/hip_bf16.h>

typedef __hip_bfloat16 bf16;
typedef unsigned short u16;
typedef unsigned int u32;

#define DD 128           // feature dim
#define NG 200           // graphs
#define NL 5             // GCN layers
#define BETA_F 0.007782140442054161f   // log(1/128 + 1)
#define BN_EPS_F 1e-5f
#define WSTRIDE 136      // padded W' row stride (bf16 elems); 128x136 per layer
#define WELEMS (DD * WSTRIDE)
#define CVT_BLOCKS 1024

typedef __attribute__((ext_vector_type(8))) short bf16x8v;
typedef __attribute__((ext_vector_type(4))) float f32x4v;

// ---- dtype-generic load/store helpers (flag-selected, wave-uniform) ----

template<typename T> struct LD;
template<> struct LD<float> {
    static __device__ __forceinline__ float f(const void* p, size_t i) {
        return ((const float*)p)[i];
    }
};
template<> struct LD<bf16> {
    static __device__ __forceinline__ float f(const void* p, size_t i) {
        return __bfloat162float(((const bf16*)p)[i]);
    }
};
template<typename T> struct ST;
template<> struct ST<float> {
    static __device__ __forceinline__ void s(void* p, size_t i, float v) {
        ((float*)p)[i] = v;
    }
};
template<> struct ST<bf16> {
    static __device__ __forceinline__ void s(void* p, size_t i, float v) {
        ((bf16*)p)[i] = __float2bfloat16(v);
    }
};

// ---------------- k_init: cvt+count (interleaved), then prepw, bounds ----------
template<typename TF>
__device__ __forceinline__ void prepw_body(int l, const void* gcn_w, const void* gcn_b,
        bf16* __restrict__ wtp, float* __restrict__ biasp) {
    int t = threadIdx.x;
    const TF* Wp = (const TF*)gcn_w + (size_t)l * DD * DD;
    const TF* bp = (const TF*)gcn_b + (size_t)l * DD;
    bf16* wo = wtp + (size_t)l * WELEMS;
    for (int idx = t; idx < DD * DD; idx += 256) {
        int k = idx >> 7, n = idx & 127;
        float wv = BETA_F * LD<TF>::f(Wp, idx) + (k == n ? (1.0f - BETA_F) : 0.0f);
        wo[n * WSTRIDE + k] = __float2bfloat16(wv);
    }
    if (t < DD) biasp[l * DD + t] = LD<TF>::f(bp, t);
}

__global__ void k_init(const int* __restrict__ src, const int* __restrict__ dst,
        int* deg_out, int* deg_in, int E, const u16* bn_g_raw, int* flag,
        const void* feat, const void* gcn_w, const void* gcn_b,
        const int* __restrict__ gid, int* gstart, bf16* wtp, float* biasp,
        bf16* hbuf, int N, int CB) {
    int b = blockIdx.x;
    int t = threadIdx.x;
    int bf = (bn_g_raw[0] == 0x3F80) ? 1 : 0;   // local detect (cached read)
    int IC = 2 * CVT_BLOCKS;
    int histTotal = IC + (CB - CVT_BLOCKS);     // CB >= CVT_BLOCKS for this problem
    if (b < histTotal) {
        int role, rid;
        if (b < IC) { role = b & 1; rid = b >> 1; }
        else        { role = 0;     rid = CVT_BLOCKS + (b - IC); }
        if (role == 1) {
            // cvt: feat -> bf16 hbuf
            int total8 = N * DD / 8;
            int i = rid * 256 + t;
            int stride = CVT_BLOCKS * 256;
            uint4* d = (uint4*)hbuf;
            if (bf) {
                const uint4* s = (const uint4*)feat;
                for (; i < total8; i += stride) d[i] = s[i];
            } else {
                const float4* s = (const float4*)feat;
                for (; i < total8; i += stride) {
                    float4 x = s[2 * i], y = s[2 * i + 1];
                    union { uint4 u; bf16 b8[8]; } o;
                    o.b8[0] = __float2bfloat16(x.x); o.b8[1] = __float2bfloat16(x.y);
                    o.b8[2] = __float2bfloat16(x.z); o.b8[3] = __float2bfloat16(x.w);
                    o.b8[4] = __float2bfloat16(y.x); o.b8[5] = __float2bfloat16(y.y);
                    o.b8[6] = __float2bfloat16(y.z); o.b8[7] = __float2bfloat16(y.w);
                    d[i] = o.u;
                }
            }
        } else {
            // degree histogram
            int e = rid * 256 + t;
            if (e < E) {
                atomicAdd(&deg_out[src[e]], 1);
                atomicAdd(&deg_in[dst[e]], 1);
            }
        }
        return;
    }
    b -= histTotal;
    if (b < NL) {
        if (bf) prepw_body<bf16 >(b, gcn_w, gcn_b, wtp, biasp);
        else    prepw_body<float>(b, gcn_w, gcn_b, wtp, biasp);
        return;
    }
    // bounds + flag
    if (t == 0) *flag = bf;
    int g = t;
    if (g <= NG) {
        if (g == NG) gstart[NG] = N;
        else {
            int lo = 0, hi = N;
            while (lo < hi) { int mid = (lo + hi) >> 1; if (gid[mid] < g) lo = mid + 1; else hi = mid; }
            gstart[g] = lo;
        }
    }
}

// ---------------- scan (3-phase) + cursor copy + norm precompute ----------------

__global__ void k_reduce_chunks(const int* __restrict__ deg, int* bsum, int N) {
    __shared__ int lds[256];
    int base = blockIdx.x * 1024;
    int s = 0;
    #pragma unroll
    for (int k = 0; k < 4; ++k) {
        int i = base + threadIdx.x + k * 256;
        if (i < N) s += deg[i];
    }
    lds[threadIdx.x] = s;
    __syncthreads();
    for (int off = 128; off > 0; off >>= 1) {
        if (threadIdx.x < off) lds[threadIdx.x] += lds[threadIdx.x + off];
        __syncthreads();
    }
    if (threadIdx.x == 0) bsum[blockIdx.x] = lds[0];
}

__global__ void k_scan_bsum(int* bsum, int B, int* row_ptr, int N, int E) {
    if (threadIdx.x == 0 && blockIdx.x == 0) {
        int acc = 0;
        for (int i = 0; i < B; ++i) { int v = bsum[i]; bsum[i] = acc; acc += v; }
        row_ptr[N] = E;
    }
}

__global__ void k_scan_chunks(const int* __restrict__ deg_in, const int* __restrict__ deg_out,
                              const int* __restrict__ bsum, int* row_ptr, int* cursor,
                              float* norm_out, float* norm_in, int N) {
    __shared__ int lds[256];
    int t = threadIdx.x;
    int base = blockIdx.x * 1024;
    int vals[4];
    int tsum = 0;
    #pragma unroll
    for (int k = 0; k < 4; ++k) {
        int i = base + t * 4 + k;
        int v = (i < N) ? deg_in[i] : 0;
        vals[k] = tsum;
        tsum += v;
        if (i < N) {
            norm_in[i] = rsqrtf((float)(v > 1 ? v : 1));
            int doo = deg_out[i];
            norm_out[i] = rsqrtf((float)(doo > 1 ? doo : 1));
        }
    }
    lds[t] = tsum;
    __syncthreads();
    for (int off = 1; off < 256; off <<= 1) {
        int add = (t >= off) ? lds[t - off] : 0;
        __syncthreads();
        lds[t] += add;
        __syncthreads();
    }
    int toff = (t > 0 ? lds[t - 1] : 0) + bsum[blockIdx.x];
    #pragma unroll
    for (int k = 0; k < 4; ++k) {
        int i = base + t * 4 + k;
        if (i < N) { int rp = toff + vals[k]; row_ptr[i] = rp; cursor[i] = rp; }
    }
}

__global__ void k_fill_csr(const int* __restrict__ src, const int* __restrict__ dst,
                           int* cursor, int* col, int E) {
    int e = blockIdx.x * blockDim.x + threadIdx.x;
    if (e < E) {
        int p = atomicAdd(&cursor[dst[e]], 1);
        col[p] = src[e];
    }
}

// ---------------- merged pool(hidden_rep[l]) + gather (BN-affine on the fly) ---
// BN scale/shift computed ONCE per block into LDS.
// blocks [0,poolCnt): pool role — pools affine(h) into pooled_l (atomic-free).
// blocks [poolCnt,...): gather role — ONE 16-LANE QUARTER-GROUP PER NODE
// (16 nodes/block, 4/wave): lane c owns dims [8c,8c+8), loops serially over the
// node's edges. No shuffles; 256B fully-coalesced row loads per group; all 64
// lanes active in the epilogue. r = 0.9*ni*sum(affine(h[src])*no) + 0.1*affine(h[node]).
template<typename TF>
__device__ __forceinline__ void gp_body(const bf16* __restrict__ h,
        const int* __restrict__ row_ptr, const int* __restrict__ col,
        const float* __restrict__ norm_out, const float* __restrict__ norm_in,
        const float* __restrict__ stats, const void* gamma, const void* beta,
        int apply, const int* __restrict__ gstart, float* __restrict__ pooled_l,
        int poolCnt, bf16* __restrict__ r, int N) {
    __shared__ float s_sc[DD], s_sh[DD];
    int t = threadIdx.x;
    if (t < DD) {
        float sc = 1.f, sh = 0.f;
        if (apply) {
            float invN = 1.0f / (float)N;
            float mu = stats[t] * invN;
            float var = fmaxf(stats[DD + t] * invN - mu * mu, 0.f);
            sc = rsqrtf(var + BN_EPS_F) * LD<TF>::f(gamma, t);
            sh = LD<TF>::f(beta, t) - mu * sc;
        }
        s_sc[t] = sc; s_sh[t] = sh;
    }
    __syncthreads();
    float lo = apply ? 0.f : -__builtin_inff();

    if (blockIdx.x < poolCnt) {
        // ---- pool role ----
        __shared__ float red[16][DD];
        int g = blockIdx.x;
        int rlo = gstart[g], rhi = gstart[g + 1];
        int c = t & 15, rg = t >> 4;
        int d0 = c * 8;
        float sc8[8], sh8[8];
        #pragma unroll
        for (int j = 0; j < 8; ++j) { sc8[j] = s_sc[d0 + j]; sh8[j] = s_sh[d0 + j]; }
        float acc[8] = {0.f, 0.f, 0.f, 0.f, 0.f, 0.f, 0.f, 0.f};
        for (int i = rlo + rg; i < rhi; i += 16) {
            union { uint4 u; u16 us[8]; } v;
            v.u = *(const uint4*)(h + ((size_t)i << 7) + d0);
            #pragma unroll
            for (int j = 0; j < 8; ++j) {
                float f = __uint_as_float((u32)v.us[j] << 16) * sc8[j] + sh8[j];
                acc[j] += fmaxf(f, lo);
            }
        }
        #pragma unroll
        for (int j = 0; j < 8; ++j) red[rg][d0 + j] = acc[j];
        __syncthreads();
        if (t < DD) {
            float s = 0.f;
            #pragma unroll
            for (int k = 0; k < 16; ++k) s += red[k][t];
            pooled_l[g * DD + t] = s;
        }
        return;
    }

    // ---- gather role: 16 lanes per node, serial edge loop, no shfl ----
    int node = (blockIdx.x - poolCnt) * 16 + (t >> 4);
    if (node >= N) return;
    int c = t & 15;
    int d0 = c << 3;
    float sc8[8], sh8[8];
    #pragma unroll
    for (int j = 0; j < 8; ++j) { sc8[j] = s_sc[d0 + j]; sh8[j] = s_sh[d0 + j]; }
    int beg = row_ptr[node], end = row_ptr[node + 1];
    float acc[8] = {0.f, 0.f, 0.f, 0.f, 0.f, 0.f, 0.f, 0.f};
    for (int e = beg; e < end; ++e) {
        int sn = col[e];
        float no = norm_out[sn];
        union { uint4 u; u16 us[8]; } v;
        v.u = *(const uint4*)(h + ((size_t)sn << 7) + d0);
        #pragma unroll
        for (int j = 0; j < 8; ++j) {
            float f = __uint_as_float((u32)v.us[j] << 16) * sc8[j] + sh8[j];
            acc[j] += fmaxf(f, lo) * no;
        }
    }
    float ni = 0.9f * norm_in[node];
    union { uint4 u; u16 us[8]; } sv;
    sv.u = *(const uint4*)(h + ((size_t)node << 7) + d0);
    union { uint4 u; bf16 b8[8]; } o;
    #pragma unroll
    for (int j = 0; j < 8; ++j) {
        float f = __uint_as_float((u32)sv.us[j] << 16) * sc8[j] + sh8[j];
        f = fmaxf(f, lo);
        o.b8[j] = __float2bfloat16(ni * acc[j] + 0.1f * f);
    }
    *(uint4*)(r + ((size_t)node << 7) + d0) = o.u;
}

__global__ void k_gather_pool(const bf16* __restrict__ h, const int* __restrict__ row_ptr,
        const int* __restrict__ col, const float* __restrict__ norm_out,
        const float* __restrict__ norm_in, const float* __restrict__ stats,
        const void* bn_g, const void* bn_b, int laff, int apply,
        const int* __restrict__ gstart, float* __restrict__ pooled_l, int poolCnt,
        const int* __restrict__ flag, bf16* __restrict__ r, int N) {
    int bf = *flag;
    size_t esz = bf ? 2u : 4u;
    const char* gp = (const char*)bn_g + (size_t)laff * DD * esz;
    const char* bp = (const char*)bn_b + (size_t)laff * DD * esz;
    if (bf) gp_body<bf16 >(h, row_ptr, col, norm_out, norm_in, stats, gp, bp, apply,
                           gstart, pooled_l, poolCnt, r, N);
    else    gp_body<float>(h, row_ptr, col, norm_out, norm_in, stats, gp, bp, apply,
                           gstart, pooled_l, poolCnt, r, N);
}

// ---------------- projection GEMM + fused column stats ----------------
__global__ void k_gemm(const bf16* __restrict__ r, const bf16* __restrict__ wt,
                       const float* __restrict__ biasf, bf16* __restrict__ h_out,
                       float* __restrict__ stats, int N) {
    __shared__ float sred1[4][128];
    __shared__ float sred2[4][128];
    int t = threadIdx.x;
    int w = t >> 6, lane = t & 63;
    int q = lane >> 4, c = lane & 15;
    size_t mbase = (size_t)blockIdx.x * 128 + (size_t)w * 32;
    f32x4v acc[2][8];
    #pragma unroll
    for (int rt = 0; rt < 2; ++rt)
        #pragma unroll
        for (int ct = 0; ct < 8; ++ct)
            acc[rt][ct] = (f32x4v){0.f, 0.f, 0.f, 0.f};
    #pragma unroll
    for (int ks = 0; ks < 4; ++ks) {
        int k0 = ks * 32 + q * 8;
        union { uint4 u; bf16x8v v; } a0, a1;
        a0.u = *(const uint4*)(r + ((mbase + c) << 7) + k0);
        a1.u = *(const uint4*)(r + ((mbase + 16 + c) << 7) + k0);
        #pragma unroll
        for (int ct = 0; ct < 8; ++ct) {
            union { uint4 u; bf16x8v v; } b;
            b.u = *(const uint4*)(wt + (size_t)(ct * 16 + c) * WSTRIDE + k0);
            acc[0][ct] = __builtin_amdgcn_mfma_f32_16x16x32_bf16(a0.v, b.v, acc[0][ct], 0, 0, 0);
            acc[1][ct] = __builtin_amdgcn_mfma_f32_16x16x32_bf16(a1.v, b.v, acc[1][ct], 0, 0, 0);
        }
    }
    // epilogue: C layout col = lane&15, row = quad*4 + reg  [m89-verified]
    float s1[8] = {0.f, 0.f, 0.f, 0.f, 0.f, 0.f, 0.f, 0.f};
    float s2[8] = {0.f, 0.f, 0.f, 0.f, 0.f, 0.f, 0.f, 0.f};
    #pragma unroll
    for (int ct = 0; ct < 8; ++ct) {
        int coln = ct * 16 + c;
        float bs = biasf[coln];
        #pragma unroll
        for (int rt = 0; rt < 2; ++rt) {
            size_t mrow = mbase + rt * 16 + q * 4;
            #pragma unroll
            for (int reg = 0; reg < 4; ++reg) {
                size_t row = mrow + reg;
                float v = acc[rt][ct][reg] + bs;
                if (row < (size_t)N) {
                    h_out[(row << 7) + coln] = __float2bfloat16(v);
                    s1[ct] += v;
                    s2[ct] += v * v;
                }
            }
        }
    }
    #pragma unroll
    for (int j = 0; j < 8; ++j) {
        s1[j] += __shfl_xor(s1[j], 16, 64); s1[j] += __shfl_xor(s1[j], 32, 64);
        s2[j] += __shfl_xor(s2[j], 16, 64); s2[j] += __shfl_xor(s2[j], 32, 64);
    }
    if (q == 0) {
        #pragma unroll
        for (int ct = 0; ct < 8; ++ct) {
            sred1[w][ct * 16 + c] = s1[ct];
            sred2[w][ct * 16 + c] = s2[ct];
        }
    }
    __syncthreads();
    if (t < DD) {
        float a1 = sred1[0][t] + sred1[1][t] + sred1[2][t] + sred1[3][t];
        float a2 = sred2[0][t] + sred2[1][t] + sred2[2][t] + sred2[3][t];
        atomicAdd(&stats[t], a1);
        atomicAdd(&stats[DD + t], a2);
    }
}

// ---------------- head (parallelized over 128 dims) ----------------

template<typename TF>
__device__ __forceinline__ void head_body(const float* __restrict__ pooled,
        const void* lin_w, const void* lin_b, void* out) {
    int g = blockIdx.x;   // 200
    int t = threadIdx.x;  // 128
    __shared__ float red[128 * 10];
    __shared__ float scv[10];
    __shared__ float lse;
    float part[10] = {0.f, 0.f, 0.f, 0.f, 0.f, 0.f, 0.f, 0.f, 0.f, 0.f};
    float mp = 0.f;
    for (int l = 0; l < NL + 1; ++l) {
        float pl = pooled[(size_t)(l * NG + g) * DD + t];
        if (l > 0) mp += pl;
        #pragma unroll
        for (int o = 0; o < 10; ++o)
            part[o] += pl * LD<TF>::f(lin_w, (size_t)l * DD * 10 + (size_t)t * 10 + o);
    }
    #pragma unroll
    for (int o = 0; o < 10; ++o) red[t * 10 + o] = part[o];
    __syncthreads();
    for (int off = 64; off >= 1; off >>= 1) {
        if (t < off) {
            #pragma unroll
            for (int o = 0; o < 10; ++o) red[t * 10 + o] += red[(t + off) * 10 + o];
        }
        __syncthreads();
    }
    if (t < 10) {
        float s = red[t];
        for (int l = 0; l < NL + 1; ++l) s += LD<TF>::f(lin_b, l * 10 + t);
        scv[t] = s;
    }
    __syncthreads();
    if (t == 0) {
        float m = scv[0];
        for (int o = 1; o < 10; ++o) m = fmaxf(m, scv[o]);
        float su = 0.f;
        for (int o = 0; o < 10; ++o) su += expf(scv[o] - m);
        lse = m + logf(su);
    }
    __syncthreads();
    if (t < 10) ST<TF>::s(out, g * 10 + t, scv[t] - lse);
    ST<TF>::s(out, NG * 10 + (size_t)g * DD + t, mp * 0.2f);
}

__global__ void k_head(const float* __restrict__ pooled, const int* __restrict__ flag,
        const void* lin_w, const void* lin_b, void* out) {
    if (*flag) head_body<bf16 >(pooled, lin_w, lin_b, out);
    else       head_body<float>(pooled, lin_w, lin_b, out);
}

// ---------------- launch ----------------

extern "C" void kernel_launch(void* const* d_in, const int* in_sizes, int n_in,
                              void* d_out, int out_size, void* d_ws, size_t ws_size,
                              hipStream_t stream) {
    const void* feat  = d_in[0];
    const int*  src   = (const int*)d_in[1];
    const int*  dst   = (const int*)d_in[2];
    const int*  gid   = (const int*)d_in[3];
    const void* gcn_w = d_in[4];
    const void* gcn_b = d_in[5];
    const void* bn_g  = d_in[6];
    const void* bn_b  = d_in[7];
    const void* lin_w = d_in[8];
    const void* lin_b = d_in[9];
    const int N = in_sizes[0] / DD;   // 100000
    const int E = in_sizes[1];        // 600000
    const int Mpad = ((N + 127) / 128) * 128;

    char* wsb = (char*)d_ws;
    size_t off = 0;
    auto carve = [&](size_t bytes) -> void* {
        void* p = wsb + off;
        off = (off + bytes + 255) & ~(size_t)255;
        return p;
    };
    int*   flag     = (int*)carve(4);
    // zeroed region: deg_out .. statsAll (one memset)
    int*   deg_out  = (int*)carve((size_t)N * 4);
    int*   deg_in   = (int*)carve((size_t)N * 4);
    float* statsAll = (float*)carve((size_t)NL * 2 * DD * 4);
    // un-zeroed scratch
    int*   row_ptr  = (int*)carve((size_t)(N + 1) * 4);
    int*   cursor   = (int*)carve((size_t)N * 4);
    int*   col      = (int*)carve((size_t)E * 4);
    int*   bsum     = (int*)carve(1024 * 4);
    int*   gstart   = (int*)carve((size_t)(NG + 1) * 4);
    float* norm_out = (float*)carve((size_t)N * 4);
    float* norm_in  = (float*)carve((size_t)N * 4);
    bf16*  wtp      = (bf16*)carve((size_t)NL * WELEMS * 2);
    float* biasp    = (float*)carve((size_t)NL * DD * 4);
    float* pooled   = (float*)carve((size_t)(NL + 1) * NG * DD * 4);
    bf16*  hA       = (bf16*)carve((size_t)Mpad * DD * 2);
    bf16*  hB       = (bf16*)carve((size_t)Mpad * DD * 2);
    bf16*  rbuf     = (bf16*)carve((size_t)Mpad * DD * 2);

    if (off > ws_size) return;   // guard: leave d_out zeroed (distinguishable)

    hipMemsetAsync(deg_out, 0,
                   (size_t)((char*)statsAll - (char*)deg_out) + (size_t)NL * 2 * DD * 4,
                   stream);

    const int CB = (E + 255) / 256;
    k_init<<<CVT_BLOCKS + CB + NL + 1, 256, 0, stream>>>(
        src, dst, deg_out, deg_in, E, (const u16*)bn_g, flag,
        feat, gcn_w, gcn_b, gid, gstart, wtp, biasp, hA, N, CB);

    int B = (N + 1023) / 1024;
    k_reduce_chunks<<<B, 256, 0, stream>>>(deg_in, bsum, N);
    k_scan_bsum<<<1, 64, 0, stream>>>(bsum, B, row_ptr, N, E);
    k_scan_chunks<<<B, 256, 0, stream>>>(deg_in, deg_out, bsum, row_ptr, cursor,
                                         norm_out, norm_in, N);
    k_fill_csr<<<(E + 255) / 256, 256, 0, stream>>>(src, dst, cursor, col, E);

    const int GB = (N + 15) / 16;   // gather blocks: 16 nodes per block
    bf16* bufs[2] = { hA, hB };
    for (int l = 0; l < NL; ++l) {
        bf16* hin  = bufs[l & 1];
        bf16* hout = bufs[(l + 1) & 1];
        float* stats  = statsAll + (size_t)l * 2 * DD;                      // written by gemm[l]
        float* statsP = statsAll + (size_t)(l > 0 ? l - 1 : 0) * 2 * DD;    // prev layer's
        // pool role pools hidden_rep[l] (= affine(hin); raw h0 for l==0) into pooled[l]
        k_gather_pool<<<NG + GB, 256, 0, stream>>>(
            hin, row_ptr, col, norm_out, norm_in, statsP, bn_g, bn_b,
            l > 0 ? l - 1 : 0, l > 0 ? 1 : 0, gstart,
            pooled + (size_t)l * NG * DD, NG, flag, rbuf, N);
        k_gemm<<<Mpad / 128, 256, 0, stream>>>(rbuf, wtp + (size_t)l * WELEMS,
                                               biasp + (size_t)l * DD, hout, stats, N);
    }

    // final pool: hidden_rep[NL] from gemm[NL-1] output (stats[NL-1], bn[NL-1])
    k_gather_pool<<<NG, 256, 0, stream>>>(
        bufs[NL & 1], row_ptr, col, norm_out, norm_in,
        statsAll + (size_t)(NL - 1) * 2 * DD, bn_g, bn_b, NL - 1, 1, gstart,
        pooled + (size_t)NL * NG * DD, NG, flag, rbuf, N);

    k_head<<<NG, DD, 0, stream>>>(pooled, flag, lin_w, lin_b, d_out);
}